// Round 1
// baseline (4046.955 us; speedup 1.0000x reference)
//
#include <hip/hip_runtime.h>
#include <math.h>

#define N_ATOMS 20000
#define N_EDGES 200000
#define CH 64
#define NB 8
#define NK 11

// ---------------- edge stage: messages + atomic scatter ----------------
// one wave (64 lanes) per edge, lane = channel c
__global__ __launch_bounds__(256) void edge_kernel(
    const float* __restrict__ node0, const float* __restrict__ node1,
    const float* __restrict__ node2, const float* __restrict__ rij,
    const int* __restrict__ idx_i, const int* __restrict__ idx_j,
    const float* __restrict__ rbf_w,
    float* __restrict__ A0, float* __restrict__ A1, float* __restrict__ A2)
{
    int tid = blockIdx.x * blockDim.x + threadIdx.x;
    int e = tid >> 6;
    int c = tid & 63;
    if (e >= N_EDGES) return;

    float rx = rij[e * 3 + 0];
    float ry = rij[e * 3 + 1];
    float rz = rij[e * 3 + 2];
    float d = sqrtf(rx * rx + ry * ry + rz * rz);
    float inv = 1.0f / (d + 1e-12f);
    float rh[3] = { rx * inv, ry * inv, rz * inv };

    float dc = fminf(d, 5.0f);
    float fcut = 0.5f * (cosf(3.14159265358979323846f * dc * 0.2f) + 1.0f);

    float rbf[NB];
#pragma unroll
    for (int b = 0; b < NB; ++b) {
        float mu = (5.0f / 7.0f) * (float)b;
        float t = d - mu;
        rbf[b] = expf(-2.0f * t * t) * fcut;
    }

    // fc[k][c] = sum_b rbf[b] * rbf_w[k][b][c]
    float fc[NK];
#pragma unroll
    for (int k = 0; k < NK; ++k) {
        float s = 0.0f;
#pragma unroll
        for (int b = 0; b < NB; ++b)
            s = fmaf(rbf[b], rbf_w[(k * NB + b) * CH + c], s);
        fc[k] = s;
    }

    int j = idx_j[e];
    int i = idx_i[e];

    float h0 = node0[(size_t)j * CH + c];
    float h1[3];
#pragma unroll
    for (int x = 0; x < 3; ++x) h1[x] = node1[((size_t)j * CH + c) * 3 + x];
    float h2[9];
#pragma unroll
    for (int q = 0; q < 9; ++q) h2[q] = node2[((size_t)j * CH + c) * 9 + q];

    // invariants
    float u1 = h1[0] * rh[0] + h1[1] * rh[1] + h1[2] * rh[2];
    float v2[3];
#pragma unroll
    for (int x = 0; x < 3; ++x)
        v2[x] = h2[x * 3 + 0] * rh[0] + h2[x * 3 + 1] * rh[1] + h2[x * 3 + 2] * rh[2];
    float w2 = v2[0] * rh[0] + v2[1] * rh[1] + v2[2] * rh[2];

    // way-0 message
    float m0 = fc[0] * h0 + fc[4] * u1 + fc[9] * w2;
    atomicAdd(&A0[(size_t)i * CH + c], m0);

    // way-1 message: m1[x] = (fc1*h0 + fc6*u1)*rh[x] + fc3*h1[x] + fc8*v2[x]
    float c1 = fc[1] * h0 + fc[6] * u1;
#pragma unroll
    for (int x = 0; x < 3; ++x) {
        float m1 = c1 * rh[x] + fc[3] * h1[x] + fc[8] * v2[x];
        atomicAdd(&A1[((size_t)i * CH + c) * 3 + x], m1);
    }

    // way-2 message: m2[x][y] = (fc2*h0*rh[x] + fc5*h1[x] + fc10*v2[x])*rh[y] + fc7*h2[x][y]
#pragma unroll
    for (int x = 0; x < 3; ++x) {
        float cx = fc[2] * h0 * rh[x] + fc[5] * h1[x] + fc[10] * v2[x];
#pragma unroll
        for (int y = 0; y < 3; ++y) {
            float m2 = cx * rh[y] + fc[7] * h2[x * 3 + y];
            atomicAdd(&A2[(((size_t)i * CH + c) * 3 + x) * 3 + y], m2);
        }
    }
}

// ---------------- atom stage: SI matmuls + gated nonlinearity + residual ----------------
// one wave per atom, lane = output channel d; 4 atoms per block
__global__ __launch_bounds__(256) void atom_kernel(
    const float* __restrict__ A0, const float* __restrict__ A1,
    const float* __restrict__ A2,
    const float* __restrict__ node0, const float* __restrict__ node1,
    const float* __restrict__ node2,
    const float* __restrict__ si_w0, const float* __restrict__ si_b0,
    const float* __restrict__ si_w1, const float* __restrict__ si_w2,
    const float* __restrict__ nl_w1, const float* __restrict__ nl_b1,
    const float* __restrict__ nl_w2, const float* __restrict__ nl_b2,
    float* __restrict__ out0, float* __restrict__ out1, float* __restrict__ out2)
{
    __shared__ float abuf[4][CH * 13];
    int wave = threadIdx.x >> 6;
    int d = threadIdx.x & 63;
    int n = blockIdx.x * 4 + wave;   // grid sized exactly: N_ATOMS % 4 == 0

    float* ab = abuf[wave];
    const float SC = 0.1f;  // 1/NORM_FACTOR

    // stage this atom's accumulators into LDS, channel-major [c][13]
    ab[d * 13 + 0] = A0[(size_t)n * CH + d] * SC;
#pragma unroll
    for (int x = 0; x < 3; ++x)
        ab[d * 13 + 1 + x] = A1[((size_t)n * CH + d) * 3 + x] * SC;
#pragma unroll
    for (int q = 0; q < 9; ++q)
        ab[d * 13 + 4 + q] = A2[((size_t)n * CH + d) * 9 + q] * SC;

    __syncthreads();

    float s0 = si_b0[d];
    float s1[3] = { 0.f, 0.f, 0.f };
    float s2[9] = { 0.f, 0.f, 0.f, 0.f, 0.f, 0.f, 0.f, 0.f, 0.f };

    for (int cc = 0; cc < CH; ++cc) {
        float w0 = si_w0[cc * CH + d];
        float w1 = si_w1[cc * CH + d];
        float w2 = si_w2[cc * CH + d];
        const float* a = &ab[cc * 13];
        s0 = fmaf(a[0], w0, s0);
#pragma unroll
        for (int x = 0; x < 3; ++x) s1[x] = fmaf(a[1 + x], w1, s1[x]);
#pragma unroll
        for (int q = 0; q < 9; ++q) s2[q] = fmaf(a[4 + q], w2, s2[q]);
    }

    // nonlinearities
    float r0 = s0 / (1.0f + expf(-s0));  // silu

    float n1 = sqrtf(s1[0] * s1[0] + s1[1] * s1[1] + s1[2] * s1[2] + 1e-6f);
    float g1 = n1 * nl_w1[d] + nl_b1[d];
    float gate1 = g1 / (1.0f + expf(-g1));

    float n2sq = 1e-6f;
#pragma unroll
    for (int q = 0; q < 9; ++q) n2sq = fmaf(s2[q], s2[q], n2sq);
    float n2 = sqrtf(n2sq);
    float g2 = n2 * nl_w2[d] + nl_b2[d];
    float gate2 = g2 / (1.0f + expf(-g2));

    // residual add + store
    out0[(size_t)n * CH + d] = node0[(size_t)n * CH + d] + r0;
#pragma unroll
    for (int x = 0; x < 3; ++x)
        out1[((size_t)n * CH + d) * 3 + x] = node1[((size_t)n * CH + d) * 3 + x] + s1[x] * gate1;
#pragma unroll
    for (int q = 0; q < 9; ++q)
        out2[((size_t)n * CH + d) * 9 + q] = node2[((size_t)n * CH + d) * 9 + q] + s2[q] * gate2;
}

extern "C" void kernel_launch(void* const* d_in, const int* in_sizes, int n_in,
                              void* d_out, int out_size, void* d_ws, size_t ws_size,
                              hipStream_t stream) {
    const float* node0 = (const float*)d_in[0];
    const float* node1 = (const float*)d_in[1];
    const float* node2 = (const float*)d_in[2];
    const float* edge0 = (const float*)d_in[3];
    const float* rij   = (const float*)d_in[4];
    const int*   idx_i = (const int*)d_in[5];
    const int*   idx_j = (const int*)d_in[6];
    const float* rbf_w = (const float*)d_in[7];
    const float* si_w0 = (const float*)d_in[8];
    const float* si_b0 = (const float*)d_in[9];
    const float* si_w1 = (const float*)d_in[10];
    const float* si_w2 = (const float*)d_in[11];
    const float* nl_w1 = (const float*)d_in[12];
    const float* nl_b1 = (const float*)d_in[13];
    const float* nl_w2 = (const float*)d_in[14];
    const float* nl_b2 = (const float*)d_in[15];

    float* out = (float*)d_out;
    float* out0 = out;                                   // [A, C]
    float* out1 = out + (size_t)N_ATOMS * CH;            // [A, C, 3]
    float* out2 = out1 + (size_t)N_ATOMS * CH * 3;       // [A, C, 3, 3]
    float* oute = out2 + (size_t)N_ATOMS * CH * 9;       // [E, C]

    float* A0 = (float*)d_ws;
    float* A1 = A0 + (size_t)N_ATOMS * CH;
    float* A2 = A1 + (size_t)N_ATOMS * CH * 3;
    size_t accBytes = (size_t)N_ATOMS * CH * 13 * sizeof(float);

    hipMemsetAsync(d_ws, 0, accBytes, stream);

    edge_kernel<<<(N_EDGES + 3) / 4, 256, 0, stream>>>(
        node0, node1, node2, rij, idx_i, idx_j, rbf_w, A0, A1, A2);

    atom_kernel<<<N_ATOMS / 4, 256, 0, stream>>>(
        A0, A1, A2, node0, node1, node2,
        si_w0, si_b0, si_w1, si_w2, nl_w1, nl_b1, nl_w2, nl_b2,
        out0, out1, out2);

    hipMemcpyAsync(oute, edge0, (size_t)N_EDGES * CH * sizeof(float),
                   hipMemcpyDeviceToDevice, stream);
}

// Round 2
// 305.373 us; speedup vs baseline: 13.2525x; 13.2525x over previous
//
#include <hip/hip_runtime.h>
#include <math.h>

#define N_ATOMS 20000
#define N_EDGES 200000
#define CH 64
#define NB 8
#define NK 11

// ---------------------------------------------------------------
// Kernel 1: per-edge geometry (SoA) + histogram of idx_i
// geom layout: [comp][E], comp 0..2 = rhat, 3..10 = rbf*fcut
__global__ __launch_bounds__(256) void edge_prep_kernel(
    const float* __restrict__ rij, const int* __restrict__ idx_i,
    float* __restrict__ geom, int* __restrict__ counts)
{
    int e = blockIdx.x * blockDim.x + threadIdx.x;
    if (e >= N_EDGES) return;

    float rx = rij[e * 3 + 0];
    float ry = rij[e * 3 + 1];
    float rz = rij[e * 3 + 2];
    float d = sqrtf(rx * rx + ry * ry + rz * rz);
    float inv = 1.0f / (d + 1e-12f);
    geom[0 * N_EDGES + e] = rx * inv;
    geom[1 * N_EDGES + e] = ry * inv;
    geom[2 * N_EDGES + e] = rz * inv;

    float dc = fminf(d, 5.0f);
    float fcut = 0.5f * (cosf(3.14159265358979323846f * dc * 0.2f) + 1.0f);
#pragma unroll
    for (int b = 0; b < NB; ++b) {
        float mu = (5.0f / 7.0f) * (float)b;
        float t = d - mu;
        geom[(3 + b) * N_EDGES + e] = expf(-2.0f * t * t) * fcut;
    }

    atomicAdd(&counts[idx_i[e]], 1);
}

// ---------------------------------------------------------------
// Kernel 2: exclusive scan of counts -> offsets, cursor (single block)
__global__ __launch_bounds__(256) void scan_kernel(
    const int* __restrict__ counts, int* __restrict__ offsets,
    int* __restrict__ cursor)
{
    __shared__ int part[256];
    const int CHUNK = 80;  // 256*80 = 20480 >= 20000
    int t = threadIdx.x;
    int beg = t * CHUNK;
    int s = 0;
    for (int k = 0; k < CHUNK; ++k) {
        int idx = beg + k;
        if (idx < N_ATOMS) s += counts[idx];
    }
    part[t] = s;
    __syncthreads();
    for (int off = 1; off < 256; off <<= 1) {
        int v = (t >= off) ? part[t - off] : 0;
        __syncthreads();
        part[t] += v;
        __syncthreads();
    }
    int run = part[t] - s;  // exclusive base for this thread's chunk
    for (int k = 0; k < CHUNK; ++k) {
        int idx = beg + k;
        if (idx < N_ATOMS) {
            offsets[idx] = run;
            cursor[idx] = run;
            run += counts[idx];
        }
    }
    if (t == 0) offsets[N_ATOMS] = N_EDGES;
}

// ---------------------------------------------------------------
// Kernel 3: scatter edge ids into CSR order
__global__ __launch_bounds__(256) void scatter_kernel(
    const int* __restrict__ idx_i, int* __restrict__ cursor,
    int* __restrict__ csr)
{
    int e = blockIdx.x * blockDim.x + threadIdx.x;
    if (e >= N_EDGES) return;
    int i = idx_i[e];
    int p = atomicAdd(&cursor[i], 1);
    csr[p] = e;
}

// ---------------------------------------------------------------
// Kernel 4: fused per-atom gather + SI matmul + nonlinearity + residual
// one wave per atom, lane = channel; 4 atoms per block
__global__ __launch_bounds__(256) void atom_fused_kernel(
    const float* __restrict__ node0, const float* __restrict__ node1,
    const float* __restrict__ node2,
    const int* __restrict__ idx_j, const int* __restrict__ csr,
    const int* __restrict__ offsets, const float* __restrict__ geom,
    const float* __restrict__ rbf_w,
    const float* __restrict__ si_w0, const float* __restrict__ si_b0,
    const float* __restrict__ si_w1, const float* __restrict__ si_w2,
    const float* __restrict__ nl_w1, const float* __restrict__ nl_b1,
    const float* __restrict__ nl_w2, const float* __restrict__ nl_b2,
    float* __restrict__ out0, float* __restrict__ out1, float* __restrict__ out2)
{
    __shared__ float abuf[4][CH][13];
    int wave = threadIdx.x >> 6;
    int c = threadIdx.x & 63;
    int n = blockIdx.x * 4 + wave;  // N_ATOMS % 4 == 0

    // hold this lane's slice of rbf_w in registers: wreg[k*NB+b] = rbf_w[k][b][c]
    float wreg[NK * NB];
#pragma unroll
    for (int kb = 0; kb < NK * NB; ++kb) wreg[kb] = rbf_w[kb * CH + c];

    float a0 = 0.f;
    float a1[3] = {0.f, 0.f, 0.f};
    float a2[9] = {0.f, 0.f, 0.f, 0.f, 0.f, 0.f, 0.f, 0.f, 0.f};

    int beg = offsets[n];
    int end = offsets[n + 1];

    for (int p = beg; p < end; ++p) {
        int e = csr[p];
        int j = idx_j[e];

        float rh[3], rbf[NB];
#pragma unroll
        for (int x = 0; x < 3; ++x) rh[x] = geom[x * N_EDGES + e];
#pragma unroll
        for (int b = 0; b < NB; ++b) rbf[b] = geom[(3 + b) * N_EDGES + e];

        float fc[NK];
#pragma unroll
        for (int k = 0; k < NK; ++k) {
            float s = 0.f;
#pragma unroll
            for (int b = 0; b < NB; ++b) s = fmaf(rbf[b], wreg[k * NB + b], s);
            fc[k] = s;
        }

        float h0 = node0[(size_t)j * CH + c];
        float h1[3];
#pragma unroll
        for (int x = 0; x < 3; ++x) h1[x] = node1[((size_t)j * CH + c) * 3 + x];
        float h2[9];
#pragma unroll
        for (int q = 0; q < 9; ++q) h2[q] = node2[((size_t)j * CH + c) * 9 + q];

        float u1 = h1[0] * rh[0] + h1[1] * rh[1] + h1[2] * rh[2];
        float v2[3];
#pragma unroll
        for (int x = 0; x < 3; ++x)
            v2[x] = h2[x * 3 + 0] * rh[0] + h2[x * 3 + 1] * rh[1] + h2[x * 3 + 2] * rh[2];
        float w2 = v2[0] * rh[0] + v2[1] * rh[1] + v2[2] * rh[2];

        a0 = fmaf(fc[0], h0, a0);
        a0 = fmaf(fc[4], u1, a0);
        a0 = fmaf(fc[9], w2, a0);

        float c1 = fc[1] * h0 + fc[6] * u1;
#pragma unroll
        for (int x = 0; x < 3; ++x)
            a1[x] += c1 * rh[x] + fc[3] * h1[x] + fc[8] * v2[x];

#pragma unroll
        for (int x = 0; x < 3; ++x) {
            float cx = fc[2] * h0 * rh[x] + fc[5] * h1[x] + fc[10] * v2[x];
#pragma unroll
            for (int y = 0; y < 3; ++y)
                a2[x * 3 + y] += cx * rh[y] + fc[7] * h2[x * 3 + y];
        }
    }

    // stage accumulators (scaled) into LDS, [c][13]
    const float SC = 0.1f;  // 1/NORM_FACTOR
    abuf[wave][c][0] = a0 * SC;
#pragma unroll
    for (int x = 0; x < 3; ++x) abuf[wave][c][1 + x] = a1[x] * SC;
#pragma unroll
    for (int q = 0; q < 9; ++q) abuf[wave][c][4 + q] = a2[q] * SC;

    __syncthreads();

    // SI channel mixing: lane = output channel d
    int d = c;
    float s0 = si_b0[d];
    float s1[3] = {0.f, 0.f, 0.f};
    float s2[9] = {0.f, 0.f, 0.f, 0.f, 0.f, 0.f, 0.f, 0.f, 0.f};

    for (int cc = 0; cc < CH; ++cc) {
        float w0 = si_w0[cc * CH + d];
        float w1 = si_w1[cc * CH + d];
        float w2m = si_w2[cc * CH + d];
        const float* a = abuf[wave][cc];
        s0 = fmaf(a[0], w0, s0);
#pragma unroll
        for (int x = 0; x < 3; ++x) s1[x] = fmaf(a[1 + x], w1, s1[x]);
#pragma unroll
        for (int q = 0; q < 9; ++q) s2[q] = fmaf(a[4 + q], w2m, s2[q]);
    }

    float r0 = s0 / (1.0f + expf(-s0));

    float n1 = sqrtf(s1[0] * s1[0] + s1[1] * s1[1] + s1[2] * s1[2] + 1e-6f);
    float g1 = n1 * nl_w1[d] + nl_b1[d];
    float gate1 = g1 / (1.0f + expf(-g1));

    float n2sq = 1e-6f;
#pragma unroll
    for (int q = 0; q < 9; ++q) n2sq = fmaf(s2[q], s2[q], n2sq);
    float n2 = sqrtf(n2sq);
    float g2 = n2 * nl_w2[d] + nl_b2[d];
    float gate2 = g2 / (1.0f + expf(-g2));

    out0[(size_t)n * CH + d] = node0[(size_t)n * CH + d] + r0;
#pragma unroll
    for (int x = 0; x < 3; ++x)
        out1[((size_t)n * CH + d) * 3 + x] =
            node1[((size_t)n * CH + d) * 3 + x] + s1[x] * gate1;
#pragma unroll
    for (int q = 0; q < 9; ++q)
        out2[((size_t)n * CH + d) * 9 + q] =
            node2[((size_t)n * CH + d) * 9 + q] + s2[q] * gate2;
}

extern "C" void kernel_launch(void* const* d_in, const int* in_sizes, int n_in,
                              void* d_out, int out_size, void* d_ws, size_t ws_size,
                              hipStream_t stream) {
    const float* node0 = (const float*)d_in[0];
    const float* node1 = (const float*)d_in[1];
    const float* node2 = (const float*)d_in[2];
    const float* edge0 = (const float*)d_in[3];
    const float* rij   = (const float*)d_in[4];
    const int*   idx_i = (const int*)d_in[5];
    const int*   idx_j = (const int*)d_in[6];
    const float* rbf_w = (const float*)d_in[7];
    const float* si_w0 = (const float*)d_in[8];
    const float* si_b0 = (const float*)d_in[9];
    const float* si_w1 = (const float*)d_in[10];
    const float* si_w2 = (const float*)d_in[11];
    const float* nl_w1 = (const float*)d_in[12];
    const float* nl_b1 = (const float*)d_in[13];
    const float* nl_w2 = (const float*)d_in[14];
    const float* nl_b2 = (const float*)d_in[15];

    float* out = (float*)d_out;
    float* out0 = out;                                   // [A, C]
    float* out1 = out + (size_t)N_ATOMS * CH;            // [A, C, 3]
    float* out2 = out1 + (size_t)N_ATOMS * CH * 3;       // [A, C, 3, 3]
    float* oute = out2 + (size_t)N_ATOMS * CH * 9;       // [E, C]

    // workspace layout
    char* ws = (char*)d_ws;
    int* counts  = (int*)ws;                              ws += N_ATOMS * sizeof(int);
    int* cursor  = (int*)ws;                              ws += N_ATOMS * sizeof(int);
    int* offsets = (int*)ws;                              ws += (N_ATOMS + 1) * sizeof(int);
    int* csr     = (int*)ws;                              ws += N_EDGES * sizeof(int);
    float* geom  = (float*)ws;                            // 12 * N_EDGES floats

    hipMemsetAsync(counts, 0, N_ATOMS * sizeof(int), stream);

    edge_prep_kernel<<<(N_EDGES + 255) / 256, 256, 0, stream>>>(
        rij, idx_i, geom, counts);

    scan_kernel<<<1, 256, 0, stream>>>(counts, offsets, cursor);

    scatter_kernel<<<(N_EDGES + 255) / 256, 256, 0, stream>>>(idx_i, cursor, csr);

    atom_fused_kernel<<<N_ATOMS / 4, 256, 0, stream>>>(
        node0, node1, node2, idx_j, csr, offsets, geom, rbf_w,
        si_w0, si_b0, si_w1, si_w2, nl_w1, nl_b1, nl_w2, nl_b2,
        out0, out1, out2);

    hipMemcpyAsync(oute, edge0, (size_t)N_EDGES * CH * sizeof(float),
                   hipMemcpyDeviceToDevice, stream);
}

// Round 3
// 210.059 us; speedup vs baseline: 19.2658x; 1.4537x over previous
//
#include <hip/hip_runtime.h>
#include <math.h>

#define N_ATOMS 20000
#define N_EDGES 200000
#define CH 64
#define NB 8
#define NK 11
#define COPY_BLOCKS 12500   // 200000*64 floats / 4 / 256 f4-per-block

// ---------------------------------------------------------------
// Kernel 1: histogram of idx_i
__global__ __launch_bounds__(256) void hist_kernel(
    const int* __restrict__ idx_i, int* __restrict__ counts)
{
    int e = blockIdx.x * blockDim.x + threadIdx.x;
    if (e >= N_EDGES) return;
    atomicAdd(&counts[idx_i[e]], 1);
}

// ---------------------------------------------------------------
// Kernel 2: exclusive scan (single 1024-thread block)
__global__ __launch_bounds__(1024) void scan_kernel(
    const int* __restrict__ counts, int* __restrict__ offsets,
    int* __restrict__ cursor)
{
    __shared__ int part[1024];
    const int CHUNK = 20;  // 1024*20 = 20480 >= 20000
    int t = threadIdx.x;
    int beg = t * CHUNK;
    int s = 0;
    for (int k = 0; k < CHUNK; ++k) {
        int idx = beg + k;
        if (idx < N_ATOMS) s += counts[idx];
    }
    part[t] = s;
    __syncthreads();
    for (int off = 1; off < 1024; off <<= 1) {
        int v = (t >= off) ? part[t - off] : 0;
        __syncthreads();
        part[t] += v;
        __syncthreads();
    }
    int run = part[t] - s;
    for (int k = 0; k < CHUNK; ++k) {
        int idx = beg + k;
        if (idx < N_ATOMS) {
            offsets[idx] = run;
            cursor[idx] = run;
            run += counts[idx];
        }
    }
    if (t == 0) offsets[N_ATOMS] = N_EDGES;
}

// ---------------------------------------------------------------
// Kernel 3: scatter into CSR order, computing geometry on the fly
// ge[p][12] = {rhx, rhy, rhz, rbf0..rbf7, pad}; jlist[p] = idx_j[e]
__global__ __launch_bounds__(256) void scatter_geom_kernel(
    const float* __restrict__ rij, const int* __restrict__ idx_i,
    const int* __restrict__ idx_j, int* __restrict__ cursor,
    int* __restrict__ jlist, float4* __restrict__ ge4)
{
    int e = blockIdx.x * blockDim.x + threadIdx.x;
    if (e >= N_EDGES) return;

    float rx = rij[e * 3 + 0];
    float ry = rij[e * 3 + 1];
    float rz = rij[e * 3 + 2];
    float d = sqrtf(rx * rx + ry * ry + rz * rz);
    float inv = 1.0f / (d + 1e-12f);

    float dc = fminf(d, 5.0f);
    float fcut = 0.5f * (cosf(3.14159265358979323846f * dc * 0.2f) + 1.0f);

    float rbf[NB];
#pragma unroll
    for (int b = 0; b < NB; ++b) {
        float mu = (5.0f / 7.0f) * (float)b;
        float t = d - mu;
        rbf[b] = expf(-2.0f * t * t) * fcut;
    }

    int p = atomicAdd(&cursor[idx_i[e]], 1);
    jlist[p] = idx_j[e];
    ge4[p * 3 + 0] = make_float4(rx * inv, ry * inv, rz * inv, rbf[0]);
    ge4[p * 3 + 1] = make_float4(rbf[1], rbf[2], rbf[3], rbf[4]);
    ge4[p * 3 + 2] = make_float4(rbf[5], rbf[6], rbf[7], 0.f);
}

// ---------------------------------------------------------------
// Kernel 4: fused gather + SI matmul + nonlinearity + residual.
// One 64-thread block per atom (lane = channel). Blocks beyond
// N_ATOMS copy edge0 -> oute (overlapped passthrough).
__global__ __launch_bounds__(64, 2) void atom_fused_kernel(
    const float* __restrict__ node0, const float* __restrict__ node1,
    const float* __restrict__ node2,
    const int* __restrict__ jlist, const int* __restrict__ offsets,
    const float4* __restrict__ ge4, const float* __restrict__ rbf_w,
    const float* __restrict__ si_w0, const float* __restrict__ si_b0,
    const float* __restrict__ si_w1, const float* __restrict__ si_w2,
    const float* __restrict__ nl_w1, const float* __restrict__ nl_b1,
    const float* __restrict__ nl_w2, const float* __restrict__ nl_b2,
    float* __restrict__ out0, float* __restrict__ out1, float* __restrict__ out2,
    const float4* __restrict__ edge0_in, float4* __restrict__ edge0_out)
{
    int n = blockIdx.x;
    int c = threadIdx.x;  // 0..63

    if (n >= N_ATOMS) {
        // edge0 passthrough: 256 float4 per block
        int cb = n - N_ATOMS;
        size_t base = (size_t)cb * 256;
#pragma unroll
        for (int k = 0; k < 4; ++k)
            edge0_out[base + k * 64 + c] = edge0_in[base + k * 64 + c];
        return;
    }

    __shared__ float abuf[CH][13];

    // rbf mixing weights resident in registers: wreg[k*NB+b] = rbf_w[k][b][c]
    float wreg[NK * NB];
#pragma unroll
    for (int kb = 0; kb < NK * NB; ++kb) wreg[kb] = rbf_w[kb * CH + c];

    float a0 = 0.f;
    float a1[3] = {0.f, 0.f, 0.f};
    float a2[9] = {0.f, 0.f, 0.f, 0.f, 0.f, 0.f, 0.f, 0.f, 0.f};

    int beg = offsets[n];
    int end = offsets[n + 1];

    // software pipeline state: geom + h for edge p, j for edge p+1
    float4 g0, g1v, g2v;
    float h0 = 0.f, h1[3] = {0.f, 0.f, 0.f};
    float h2[9] = {0.f, 0.f, 0.f, 0.f, 0.f, 0.f, 0.f, 0.f, 0.f};
    int jnx = 0;

    if (beg < end) {
        int j = jlist[beg];
        g0 = ge4[beg * 3 + 0];
        g1v = ge4[beg * 3 + 1];
        g2v = ge4[beg * 3 + 2];
        h0 = node0[(size_t)j * CH + c];
#pragma unroll
        for (int x = 0; x < 3; ++x) h1[x] = node1[((size_t)j * CH + c) * 3 + x];
#pragma unroll
        for (int q = 0; q < 9; ++q) h2[q] = node2[((size_t)j * CH + c) * 9 + q];
        jnx = (beg + 1 < end) ? jlist[beg + 1] : 0;
    }

    for (int p = beg; p < end; ++p) {
        // snapshot current edge data
        float rh[3] = {g0.x, g0.y, g0.z};
        float rbf[NB] = {g0.w, g1v.x, g1v.y, g1v.z, g1v.w, g2v.x, g2v.y, g2v.z};
        float ch0 = h0;
        float ch1[3] = {h1[0], h1[1], h1[2]};
        float ch2[9];
#pragma unroll
        for (int q = 0; q < 9; ++q) ch2[q] = h2[q];

        // issue next edge's prefetch
        if (p + 1 < end) {
            int j2 = jnx;
            g0 = ge4[(p + 1) * 3 + 0];
            g1v = ge4[(p + 1) * 3 + 1];
            g2v = ge4[(p + 1) * 3 + 2];
            h0 = node0[(size_t)j2 * CH + c];
#pragma unroll
            for (int x = 0; x < 3; ++x) h1[x] = node1[((size_t)j2 * CH + c) * 3 + x];
#pragma unroll
            for (int q = 0; q < 9; ++q) h2[q] = node2[((size_t)j2 * CH + c) * 9 + q];
            jnx = (p + 2 < end) ? jlist[p + 2] : 0;
        }

        // ---- compute with current edge ----
        float fc[NK];
#pragma unroll
        for (int k = 0; k < NK; ++k) {
            float s = 0.f;
#pragma unroll
            for (int b = 0; b < NB; ++b) s = fmaf(rbf[b], wreg[k * NB + b], s);
            fc[k] = s;
        }

        float u1 = ch1[0] * rh[0] + ch1[1] * rh[1] + ch1[2] * rh[2];
        float v2[3];
#pragma unroll
        for (int x = 0; x < 3; ++x)
            v2[x] = ch2[x * 3] * rh[0] + ch2[x * 3 + 1] * rh[1] + ch2[x * 3 + 2] * rh[2];
        float w2 = v2[0] * rh[0] + v2[1] * rh[1] + v2[2] * rh[2];

        a0 = fmaf(fc[0], ch0, a0);
        a0 = fmaf(fc[4], u1, a0);
        a0 = fmaf(fc[9], w2, a0);

        float c1 = fc[1] * ch0 + fc[6] * u1;
#pragma unroll
        for (int x = 0; x < 3; ++x)
            a1[x] += c1 * rh[x] + fc[3] * ch1[x] + fc[8] * v2[x];

#pragma unroll
        for (int x = 0; x < 3; ++x) {
            float cx = fc[2] * ch0 * rh[x] + fc[5] * ch1[x] + fc[10] * v2[x];
#pragma unroll
            for (int y = 0; y < 3; ++y)
                a2[x * 3 + y] += cx * rh[y] + fc[7] * ch2[x * 3 + y];
        }
    }

    // ---- stage scaled accumulators in LDS ----
    const float SC = 0.1f;  // 1/NORM_FACTOR
    abuf[c][0] = a0 * SC;
#pragma unroll
    for (int x = 0; x < 3; ++x) abuf[c][1 + x] = a1[x] * SC;
#pragma unroll
    for (int q = 0; q < 9; ++q) abuf[c][4 + q] = a2[q] * SC;

    __syncthreads();

    // ---- SI channel mixing (lane = output channel d) ----
    int d = c;
    float s0 = si_b0[d];
    float s1[3] = {0.f, 0.f, 0.f};
    float s2[9] = {0.f, 0.f, 0.f, 0.f, 0.f, 0.f, 0.f, 0.f, 0.f};

#pragma unroll 4
    for (int cc = 0; cc < CH; ++cc) {
        float w0 = si_w0[cc * CH + d];
        float w1 = si_w1[cc * CH + d];
        float w2m = si_w2[cc * CH + d];
        const float* a = abuf[cc];
        s0 = fmaf(a[0], w0, s0);
#pragma unroll
        for (int x = 0; x < 3; ++x) s1[x] = fmaf(a[1 + x], w1, s1[x]);
#pragma unroll
        for (int q = 0; q < 9; ++q) s2[q] = fmaf(a[4 + q], w2m, s2[q]);
    }

    float r0 = s0 / (1.0f + expf(-s0));

    float n1 = sqrtf(s1[0] * s1[0] + s1[1] * s1[1] + s1[2] * s1[2] + 1e-6f);
    float g1 = n1 * nl_w1[d] + nl_b1[d];
    float gate1 = g1 / (1.0f + expf(-g1));

    float n2sq = 1e-6f;
#pragma unroll
    for (int q = 0; q < 9; ++q) n2sq = fmaf(s2[q], s2[q], n2sq);
    float n2 = sqrtf(n2sq);
    float g2 = n2 * nl_w2[d] + nl_b2[d];
    float gate2 = g2 / (1.0f + expf(-g2));

    out0[(size_t)n * CH + d] = node0[(size_t)n * CH + d] + r0;
#pragma unroll
    for (int x = 0; x < 3; ++x)
        out1[((size_t)n * CH + d) * 3 + x] =
            node1[((size_t)n * CH + d) * 3 + x] + s1[x] * gate1;
#pragma unroll
    for (int q = 0; q < 9; ++q)
        out2[((size_t)n * CH + d) * 9 + q] =
            node2[((size_t)n * CH + d) * 9 + q] + s2[q] * gate2;
}

extern "C" void kernel_launch(void* const* d_in, const int* in_sizes, int n_in,
                              void* d_out, int out_size, void* d_ws, size_t ws_size,
                              hipStream_t stream) {
    const float* node0 = (const float*)d_in[0];
    const float* node1 = (const float*)d_in[1];
    const float* node2 = (const float*)d_in[2];
    const float* edge0 = (const float*)d_in[3];
    const float* rij   = (const float*)d_in[4];
    const int*   idx_i = (const int*)d_in[5];
    const int*   idx_j = (const int*)d_in[6];
    const float* rbf_w = (const float*)d_in[7];
    const float* si_w0 = (const float*)d_in[8];
    const float* si_b0 = (const float*)d_in[9];
    const float* si_w1 = (const float*)d_in[10];
    const float* si_w2 = (const float*)d_in[11];
    const float* nl_w1 = (const float*)d_in[12];
    const float* nl_b1 = (const float*)d_in[13];
    const float* nl_w2 = (const float*)d_in[14];
    const float* nl_b2 = (const float*)d_in[15];

    float* out = (float*)d_out;
    float* out0 = out;                                   // [A, C]
    float* out1 = out + (size_t)N_ATOMS * CH;            // [A, C, 3]
    float* out2 = out1 + (size_t)N_ATOMS * CH * 3;       // [A, C, 3, 3]
    float* oute = out2 + (size_t)N_ATOMS * CH * 9;       // [E, C]

    // workspace layout
    char* ws = (char*)d_ws;
    int* counts  = (int*)ws;                              ws += N_ATOMS * sizeof(int);
    int* cursor  = (int*)ws;                              ws += N_ATOMS * sizeof(int);
    int* offsets = (int*)ws;                              ws += (N_ATOMS + 1) * sizeof(int);
    ws = (char*)(((size_t)ws + 15) & ~(size_t)15);
    int* jlist   = (int*)ws;                              ws += N_EDGES * sizeof(int);
    ws = (char*)(((size_t)ws + 15) & ~(size_t)15);
    float4* ge4  = (float4*)ws;                           // 3 * N_EDGES float4

    hipMemsetAsync(counts, 0, N_ATOMS * sizeof(int), stream);

    hist_kernel<<<(N_EDGES + 255) / 256, 256, 0, stream>>>(idx_i, counts);

    scan_kernel<<<1, 1024, 0, stream>>>(counts, offsets, cursor);

    scatter_geom_kernel<<<(N_EDGES + 255) / 256, 256, 0, stream>>>(
        rij, idx_i, idx_j, cursor, jlist, ge4);

    atom_fused_kernel<<<N_ATOMS + COPY_BLOCKS, 64, 0, stream>>>(
        node0, node1, node2, jlist, offsets, ge4, rbf_w,
        si_w0, si_b0, si_w1, si_w2, nl_w1, nl_b1, nl_w2, nl_b2,
        out0, out1, out2,
        (const float4*)edge0, (float4*)oute);
}